// Round 2
// baseline (236.626 us; speedup 1.0000x reference)
//
#include <hip/hip_runtime.h>
#include <stdint.h>

#define B_ 16
#define S_ 128
#define H_ 768
#define K_ 4
#define L_ 2
#define T_ (B_*S_)   // 2048

typedef __attribute__((ext_vector_type(4))) float f32x4;
typedef __attribute__((ext_vector_type(8))) short s16x8;
typedef __bf16 bf16x8 __attribute__((ext_vector_type(8)));
typedef unsigned short u16;

// ---------- bf16 helpers ----------
__device__ inline u16 f2bf(float f) {
    union { float f; uint32_t u; } v; v.f = f;
    uint32_t u = v.u;
    return (u16)((u + 0x7fffu + ((u >> 16) & 1u)) >> 16);
}

__device__ inline ushort4 f2bf4(float4 v) {
    ushort4 r; r.x = f2bf(v.x); r.y = f2bf(v.y); r.z = f2bf(v.z); r.w = f2bf(v.w);
    return r;
}

// ---------- MFMA wrapper: tolerant to either builtin signature (short8 / bf16x8) ----------
template <typename T>
__device__ inline auto mfma_impl(T a, T b, f32x4 c, int)
    -> decltype(__builtin_amdgcn_mfma_f32_16x16x32_bf16(a, b, c, 0, 0, 0)) {
    return __builtin_amdgcn_mfma_f32_16x16x32_bf16(a, b, c, 0, 0, 0);
}
template <typename T>
__device__ inline f32x4 mfma_impl(T a, T b, f32x4 c, long) {
    return __builtin_amdgcn_mfma_f32_16x16x32_bf16(
        __builtin_bit_cast(bf16x8, a), __builtin_bit_cast(bf16x8, b), c, 0, 0, 0);
}
__device__ inline f32x4 mfma16(s16x8 a, s16x8 b, f32x4 c) {
    return mfma_impl(a, b, c, 0);
}

// ---------- async global->LDS, 16B/lane ----------
__device__ inline void gload_lds16(const void* g, void* l) {
    __builtin_amdgcn_global_load_lds(
        (__attribute__((address_space(1))) void*)(g),
        (__attribute__((address_space(3))) void*)(l), 16, 0, 0);
}

// ---- 256-thread (4-wave) stage of a 128x64-bf16 tile (used by gemm2) ----
__device__ inline void stage_tile(const char* gbase, int rowStrideBytes, u16* lds, int tid) {
    const int lane = tid & 63;
    const int w = tid >> 6;           // wave id (0..3)
    const int lr = lane >> 3;         // row within 8-row segment
    const int cb = (lane & 7) << 4;   // byte col within 128-byte row
    #pragma unroll
    for (int j = 0; j < 4; ++j) {
        const int seg = j * 4 + w;          // 0..15, wave-uniform
        const int row = seg * 8 + lr;       // 0..127
        const int sb = cb ^ ((row & 7) << 4);
        gload_lds16(gbase + (size_t)row * rowStrideBytes + sb,
                    lds + seg * 512);
    }
}

// ---- 512-thread (8-wave) stage of a 128x64-bf16 tile: 2 issues/thread ----
__device__ inline void stage128(const char* gRow0, int rowStrideBytes, char* ldsBase, int tid) {
    const int lane = tid & 63;
    const int w = tid >> 6;           // 0..7
    const int lr = lane >> 3;
    #pragma unroll
    for (int j = 0; j < 2; ++j) {
        const int seg = w * 2 + j;          // 0..15, wave-uniform
        const int row = seg * 8 + lr;       // 0..127
        const int sb = ((lane & 7) << 4) ^ ((row & 7) << 4);
        gload_lds16(gRow0 + (size_t)row * rowStrideBytes + sb,
                    ldsBase + seg * 1024);
    }
}

// Swizzled ds_read_b128 of an MFMA fragment (8 bf16 along K at one row).
// Works for tiles of 128 or 256 rows stored contiguously (row stride 128 B).
__device__ inline s16x8 read_frag(const u16* lds, int row, int colByte) {
    const int bir = colByte ^ ((row & 7) << 4);
    return *(const s16x8*)((const char*)lds + row * 128 + bir);
}

// ---------- prep kernels ----------
__global__ void prep_weights(const float* __restrict__ Wg_in, const float* __restrict__ Wg_out,
                             const float* __restrict__ W_in,  const float* __restrict__ W_out,
                             const float* __restrict__ W_loop, const float* __restrict__ sent,
                             u16* __restrict__ Wg_all, u16* __restrict__ W_all,
                             u16* __restrict__ Wl, u16* __restrict__ X0) {
    const int i4 = blockIdx.x * blockDim.x + threadIdx.x;   // float4 index
    const int NW4 = L_ * K_ * H_ * H_ / 4;                  // 1,179,648
    const int KHH4 = K_ * H_ * H_ / 4;                      // 589,824
    if (i4 < NW4) {
        const int l = i4 / KHH4;
        const int rem = i4 - l * KHH4;
        const int d0 = (l * 2) * KHH4 + rem;
        const int d1 = d0 + KHH4;
        ((ushort4*)Wg_all)[d0] = f2bf4(((const float4*)Wg_in)[i4]);
        ((ushort4*)Wg_all)[d1] = f2bf4(((const float4*)Wg_out)[i4]);
        ((ushort4*)W_all)[d0]  = f2bf4(((const float4*)W_in)[i4]);
        ((ushort4*)W_all)[d1]  = f2bf4(((const float4*)W_out)[i4]);
    }
    if (i4 < L_ * H_ * H_ / 4)  ((ushort4*)Wl)[i4] = f2bf4(((const float4*)W_loop)[i4]);
    if (i4 < T_ * H_ / 4)       ((ushort4*)X0)[i4] = f2bf4(((const float4*)sent)[i4]);
}

// adjA[p][b][t][s]: p=dir*4+k; dir 0 (in): adj[b,k,s,t] (transposed), dir 1 (out): adj[b,k,t,s]
__global__ void prep_adj(const float* __restrict__ adj, u16* __restrict__ adjA) {
    const int idx = blockIdx.x * blockDim.x + threadIdx.x;   // 0 .. 2^21-1
    const int s = idx & 127;
    const int t = (idx >> 7) & 127;
    const int b = (idx >> 14) & 15;
    const int p = idx >> 18;
    const int dir = p >> 2, k = p & 3;
    const float v = dir ? adj[(((size_t)b * K_ + k) * S_ + t) * S_ + s]
                        : adj[(((size_t)b * K_ + k) * S_ + s) * S_ + t];
    adjA[idx] = f2bf(v);
}

// ---------- GEMM 1: gated weight GEMMs + self loop (8-phase-class pipeline) ----------
// Tile: 256 tokens x 256 virtual-N (rel 0-127 | gate 128-255), BK=64, 8 waves 2x4.
// grid (6 n-tiles, 8 m-tiles, 9 problems), block 512.

#define RD_A(QI)                                                                  \
    { _Pragma("unroll") for (int i = 0; i < 4; ++i) {                             \
        _Pragma("unroll") for (int kk = 0; kk < 2; ++kk) {                        \
            a[i][kk] = read_frag(lA, wm*128 + (QI)*64 + i*16 + l15, kk*64 + hi16);\
        } } }

#define RD_B(QJ)                                                                  \
    { _Pragma("unroll") for (int j = 0; j < 2; ++j) {                             \
        _Pragma("unroll") for (int kk = 0; kk < 2; ++kk) {                        \
            b[j][kk] = read_frag(lB, wn*64 + (QJ)*32 + j*16 + l15, kk*64 + hi16); \
        } } }

#define MFMA_Q(QI, QJ)                                                            \
    { _Pragma("unroll") for (int i = 0; i < 4; ++i) {                             \
        _Pragma("unroll") for (int j = 0; j < 2; ++j) {                           \
            _Pragma("unroll") for (int kk = 0; kk < 2; ++kk) {                    \
                acc[(QI)*4+i][(QJ)*2+j] =                                         \
                    mfma16(a[i][kk], b[j][kk], acc[(QI)*4+i][(QJ)*2+j]);          \
            } } } }

#define PHASE_SYNC_PRE                                                            \
    __builtin_amdgcn_s_barrier();                                                 \
    asm volatile("s_waitcnt lgkmcnt(0)" ::: "memory");                            \
    __builtin_amdgcn_s_setprio(1);

#define PHASE_SYNC_POST                                                           \
    __builtin_amdgcn_s_setprio(0);                                                \
    __builtin_amdgcn_s_barrier();

__global__ __launch_bounds__(512, 2)
void gemm1_kernel(const u16* __restrict__ Xb,
                  const u16* __restrict__ Wg_all, const u16* __restrict__ W_all,
                  const u16* __restrict__ Wl,
                  const float* __restrict__ bg_in, const float* __restrict__ bg_out,
                  const float* __restrict__ b_in,  const float* __restrict__ b_out,
                  int layer,
                  u16* __restrict__ Rel2, float* __restrict__ SBuf) {
    __shared__ __align__(16) char smem[131072];   // 2 dbuf x (A 32K + B 32K); epilogue: sig[256][128] f32

    const int tid = threadIdx.x;
    const int lane = tid & 63;
    const int w = tid >> 6;
    const int wm = w >> 2;                 // 0..1
    const int wn = w & 3;                  // 0..3
    const int l15 = lane & 15;
    const int hi16 = (lane >> 4) << 4;     // byte col offset within 64-byte kk half
    const int p = blockIdx.z;
    const bool gated = (p < 8);
    if (!gated && blockIdx.x >= 3) return;
    const int m0 = blockIdx.y * 256;
    const int n0 = gated ? blockIdx.x * 128 : blockIdx.x * 256;

    const u16* Wr;
    const u16* Wg = nullptr;
    if (gated) {
        const int dir = p >> 2, k = p & 3;
        const size_t woff = ((size_t)(layer * 2 + dir) * K_ + k) * (size_t)(H_ * H_);
        Wg = Wg_all + woff;
        Wr = W_all + woff;
    } else {
        Wr = Wl + (size_t)layer * H_ * H_;
    }

    const char* gA  = (const char*)Xb + (size_t)m0 * (H_ * 2);
    const char* gB0 = (const char*)Wr + (size_t)n0 * (H_ * 2);
    const char* gB1 = gated ? ((const char*)Wg + (size_t)n0 * (H_ * 2))
                            : (gB0 + (size_t)128 * (H_ * 2));

    auto STAGE_A = [&](int kt, int c) {
        char* base = smem + c * 65536;
        stage128(gA + (size_t)kt * 128, H_ * 2, base, tid);
        stage128(gA + (size_t)128 * (H_ * 2) + (size_t)kt * 128, H_ * 2, base + 16384, tid);
    };
    auto STAGE_B = [&](int kt, int c) {
        char* base = smem + c * 65536 + 32768;
        stage128(gB0 + (size_t)kt * 128, H_ * 2, base, tid);
        stage128(gB1 + (size_t)kt * 128, H_ * 2, base + 16384, tid);
    };

    const f32x4 zf = {0.f, 0.f, 0.f, 0.f};
    f32x4 acc[8][4];
    #pragma unroll
    for (int i = 0; i < 8; ++i)
        #pragma unroll
        for (int j = 0; j < 4; ++j) acc[i][j] = zf;
    s16x8 a[4][2], b[2][2];

    // prologue: tiles 0 and 1 fully staged; wait for tile 0 (8 oldest of 16)
    STAGE_A(0, 0); STAGE_B(0, 0);
    STAGE_A(1, 1); STAGE_B(1, 1);
    asm volatile("s_waitcnt vmcnt(8)" ::: "memory");
    __builtin_amdgcn_s_barrier();

    for (int t = 0; t < 12; ++t) {
        const int c = t & 1;
        const u16* lA = (const u16*)(smem + c * 65536);
        const u16* lB = (const u16*)(smem + c * 65536 + 32768);
        const bool st = (t >= 1) && (t < 11);   // stage tile t+1 into buf c^1 (freed at end of t-1)

        // phase 0: quadrant (0,0); prefetch A of tile t+1
        RD_A(0); RD_B(0);
        if (st) STAGE_A(t + 1, c ^ 1);
        PHASE_SYNC_PRE
        MFMA_Q(0, 0)
        PHASE_SYNC_POST

        // phase 1: quadrant (0,1); prefetch B of tile t+1
        RD_B(1);
        if (st) STAGE_B(t + 1, c ^ 1);
        PHASE_SYNC_PRE
        MFMA_Q(0, 1)
        PHASE_SYNC_POST

        // phase 2: quadrant (1,0)
        RD_A(1); RD_B(0);
        PHASE_SYNC_PRE
        MFMA_Q(1, 0)
        PHASE_SYNC_POST

        // phase 3: quadrant (1,1); drain next tile's loads once per K-tile
        RD_B(1);
        PHASE_SYNC_PRE
        MFMA_Q(1, 1)
        __builtin_amdgcn_s_setprio(0);
        asm volatile("s_waitcnt vmcnt(0)" ::: "memory");
        __builtin_amdgcn_s_barrier();
    }

    // ---------------- epilogue ----------------
    if (gated) {
        const int dir = p >> 2, k = p & 3;
        const float* bgp = (dir ? bg_out : bg_in) + ((size_t)layer * K_ + k) * H_;
        const float* brp = (dir ? b_out  : b_in ) + ((size_t)layer * K_ + k) * H_;
        float* sig = (float*)smem;             // [256 tokens][128 cols] f32, reuses staging LDS
        const int cbase = (wn & 1) * 64;
        const bool isGate = (wn >= 2);

        if (isGate) {
            #pragma unroll
            for (int n = 0; n < 4; ++n) {
                const int cc = cbase + (n >> 1) * 32 + (n & 1) * 16 + l15;
                const float bgv = bgp[n0 + cc];
                #pragma unroll
                for (int m = 0; m < 8; ++m) {
                    const int tl0 = wm * 128 + (m >> 2) * 64 + (m & 3) * 16 + ((lane >> 4) << 2);
                    #pragma unroll
                    for (int r = 0; r < 4; ++r) {
                        const float g = acc[m][n][r] + bgv;
                        sig[(tl0 + r) * 128 + cc] = 1.f / (1.f + __expf(-g));
                    }
                }
            }
        }
        __syncthreads();
        if (!isGate) {
            const int bb = blockIdx.y * 2;
            #pragma unroll
            for (int n = 0; n < 4; ++n) {
                const int cc = cbase + (n >> 1) * 32 + (n & 1) * 16 + l15;
                const int h = n0 + cc;
                const float brv = brp[h];
                #pragma unroll
                for (int m = 0; m < 8; ++m) {
                    const int tl0 = wm * 128 + (m >> 2) * 64 + (m & 3) * 16 + ((lane >> 4) << 2);
                    const int bidx = bb + (tl0 >> 7);
                    const int s0 = tl0 & 127;
                    u16 tmp[4];
                    #pragma unroll
                    for (int r = 0; r < 4; ++r) {
                        const float v = acc[m][n][r] + brv;
                        tmp[r] = f2bf(0.5f * v * sig[(tl0 + r) * 128 + cc]);
                    }
                    ushort4 pk; pk.x = tmp[0]; pk.y = tmp[1]; pk.z = tmp[2]; pk.w = tmp[3];
                    *(ushort4*)(Rel2 + (((size_t)p * B_ + bidx) * H_ + h) * S_ + s0) = pk;
                }
            }
        }
    } else {
        #pragma unroll
        for (int n = 0; n < 4; ++n) {
            const int nv = wn * 64 + (n >> 1) * 32 + (n & 1) * 16 + l15;
            const int h = n0 + nv;
            #pragma unroll
            for (int m = 0; m < 8; ++m) {
                const int tl0 = wm * 128 + (m >> 2) * 64 + (m & 3) * 16 + ((lane >> 4) << 2);
                #pragma unroll
                for (int r = 0; r < 4; ++r)
                    SBuf[(size_t)(m0 + tl0 + r) * H_ + h] = acc[m][n][r];
            }
        }
    }
}

// ---------- GEMM 2: adjacency contraction + loop term + ReLU ----------
// grid (6 h-tiles, 16 batches), block 256 (4 waves, 2x2)
__global__ __launch_bounds__(256, 2)
void gemm2_kernel(const u16* __restrict__ adjA, const u16* __restrict__ Rel2,
                  const float* __restrict__ SBuf,
                  u16* __restrict__ Xn, float* __restrict__ Out, int lastLayer) {
    __shared__ u16 lA[128 * 64];
    __shared__ u16 lB[128 * 64];

    const int tid = threadIdx.x;
    const int lane = tid & 63;
    const int w = tid >> 6;
    const int wm = w >> 1, wn = w & 1;
    const int h0 = blockIdx.x * 128;
    const int b = blockIdx.y;

    const f32x4 zf = {0.f, 0.f, 0.f, 0.f};
    f32x4 acc[4][4];
    #pragma unroll
    for (int i = 0; i < 4; ++i)
        #pragma unroll
        for (int j = 0; j < 4; ++j) acc[i][j] = zf;

    for (int p = 0; p < 8; ++p) {
        const char* Ab = (const char*)adjA + ((size_t)p * B_ + b) * (S_ * S_ * 2);
        const char* Bb = (const char*)Rel2 + (((size_t)p * B_ + b) * H_ + h0) * (S_ * 2);
        #pragma unroll
        for (int sc = 0; sc < 2; ++sc) {
            __syncthreads();
            stage_tile(Ab + sc * 128, S_ * 2, lA, tid);
            stage_tile(Bb + sc * 128, S_ * 2, lB, tid);
            __syncthreads();
            #pragma unroll
            for (int kq = 0; kq < 2; ++kq) {
                const int cb = kq * 64 + ((lane >> 4) << 4);
                s16x8 a[4], bb[4];
                #pragma unroll
                for (int i = 0; i < 4; ++i)
                    a[i] = read_frag(lA, wm * 64 + i * 16 + (lane & 15), cb);
                #pragma unroll
                for (int j = 0; j < 4; ++j)
                    bb[j] = read_frag(lB, wn * 64 + j * 16 + (lane & 15), cb);
                #pragma unroll
                for (int i = 0; i < 4; ++i)
                    #pragma unroll
                    for (int j = 0; j < 4; ++j)
                        acc[i][j] = mfma16(a[i], bb[j], acc[i][j]);
            }
        }
    }

    #pragma unroll
    for (int i = 0; i < 4; ++i) {
        const int tl = wm * 64 + i * 16 + ((lane >> 4) << 2);
        #pragma unroll
        for (int j = 0; j < 4; ++j) {
            const int h = h0 + wn * 64 + j * 16 + (lane & 15);
            #pragma unroll
            for (int r = 0; r < 4; ++r) {
                const size_t t = (size_t)b * S_ + tl + r;
                float v = acc[i][j][r] + SBuf[t * H_ + h];
                v = fmaxf(v, 0.f);
                if (lastLayer) Out[t * H_ + h] = v;
                else           Xn[t * H_ + h] = f2bf(v);
            }
        }
    }
}

// ---------- launch ----------
extern "C" void kernel_launch(void* const* d_in, const int* in_sizes, int n_in,
                              void* d_out, int out_size, void* d_ws, size_t ws_size,
                              hipStream_t stream) {
    const float* sent   = (const float*)d_in[0];
    const float* adj    = (const float*)d_in[1];
    const float* W_in   = (const float*)d_in[2];
    const float* b_in   = (const float*)d_in[3];
    const float* W_out  = (const float*)d_in[4];
    const float* b_out  = (const float*)d_in[5];
    const float* Wg_in  = (const float*)d_in[6];
    const float* bg_in  = (const float*)d_in[7];
    const float* Wg_out = (const float*)d_in[8];
    const float* bg_out = (const float*)d_in[9];
    const float* W_loop = (const float*)d_in[10];

    char* ws = (char*)d_ws;
    u16* Wg_all = (u16*)(ws);                  // L*2*K*H*H*2   = 18,874,368 B
    u16* W_all  = (u16*)(ws + 18874368);       // 18,874,368 B
    u16* Wl     = (u16*)(ws + 37748736);       // L*H*H*2       =  2,359,296 B
    u16* adjA   = (u16*)(ws + 40108032);       // 8*B*S*S*2     =  4,194,304 B
    u16* X0     = (u16*)(ws + 44302336);       // T*H*2         =  3,145,728 B
    u16* X1     = (u16*)(ws + 47448064);       //                  3,145,728 B
    u16* Rel2   = (u16*)(ws + 50593792);       // 8*B*H*S*2     = 25,165,824 B
    float* SBuf = (float*)(ws + 75759616);     // T*H*4         =  6,291,456 B  (end 82,051,072)

    prep_weights<<<4608, 256, 0, stream>>>(Wg_in, Wg_out, W_in, W_out, W_loop, sent,
                                           Wg_all, W_all, Wl, X0);
    prep_adj<<<8192, 256, 0, stream>>>(adj, adjA);

    u16* Xc = X0;
    u16* Xn = X1;
    for (int l = 0; l < L_; ++l) {
        gemm1_kernel<<<dim3(6, 8, 9), 512, 0, stream>>>(Xc, Wg_all, W_all, Wl,
                                                        bg_in, bg_out, b_in, b_out,
                                                        l, Rel2, SBuf);
        gemm2_kernel<<<dim3(6, 16), 256, 0, stream>>>(adjA, Rel2, SBuf, Xn,
                                                      (float*)d_out, l == L_ - 1);
        u16* t = Xc; Xc = Xn; Xn = t;
    }
}

// Round 3
// 165.232 us; speedup vs baseline: 1.4321x; 1.4321x over previous
//
#include <hip/hip_runtime.h>
#include <stdint.h>

#define B_ 16
#define S_ 128
#define H_ 768
#define K_ 4
#define L_ 2
#define T_ (B_*S_)   // 2048

typedef __attribute__((ext_vector_type(4))) float f32x4;
typedef __attribute__((ext_vector_type(8))) short s16x8;
typedef __bf16 bf16x8 __attribute__((ext_vector_type(8)));
typedef unsigned short u16;

// ---------- bf16 helpers ----------
__device__ inline u16 f2bf(float f) {
    union { float f; uint32_t u; } v; v.f = f;
    uint32_t u = v.u;
    return (u16)((u + 0x7fffu + ((u >> 16) & 1u)) >> 16);
}

__device__ inline ushort4 f2bf4(float4 v) {
    ushort4 r; r.x = f2bf(v.x); r.y = f2bf(v.y); r.z = f2bf(v.z); r.w = f2bf(v.w);
    return r;
}

// ---------- MFMA wrapper: tolerant to either builtin signature (short8 / bf16x8) ----------
template <typename T>
__device__ inline auto mfma_impl(T a, T b, f32x4 c, int)
    -> decltype(__builtin_amdgcn_mfma_f32_16x16x32_bf16(a, b, c, 0, 0, 0)) {
    return __builtin_amdgcn_mfma_f32_16x16x32_bf16(a, b, c, 0, 0, 0);
}
template <typename T>
__device__ inline f32x4 mfma_impl(T a, T b, f32x4 c, long) {
    return __builtin_amdgcn_mfma_f32_16x16x32_bf16(
        __builtin_bit_cast(bf16x8, a), __builtin_bit_cast(bf16x8, b), c, 0, 0, 0);
}
__device__ inline f32x4 mfma16(s16x8 a, s16x8 b, f32x4 c) {
    return mfma_impl(a, b, c, 0);
}

// ---------- async global->LDS, 16B/lane ----------
__device__ inline void gload_lds16(const void* g, void* l) {
    __builtin_amdgcn_global_load_lds(
        (__attribute__((address_space(1))) void*)(g),
        (__attribute__((address_space(3))) void*)(l), 16, 0, 0);
}

// ---- 256-thread (4-wave) stage of a 128x64-bf16 tile ----
__device__ inline void stage_tile(const char* gbase, int rowStrideBytes, u16* lds, int tid) {
    const int lane = tid & 63;
    const int w = tid >> 6;           // 0..3
    const int lr = lane >> 3;
    const int cb = (lane & 7) << 4;
    #pragma unroll
    for (int j = 0; j < 4; ++j) {
        const int seg = j * 4 + w;          // 0..15
        const int row = seg * 8 + lr;       // 0..127
        const int sb = cb ^ ((row & 7) << 4);
        gload_lds16(gbase + (size_t)row * rowStrideBytes + sb,
                    lds + seg * 512);
    }
}

// ---- 256-thread stage of a 64x64-bf16 tile ----
__device__ inline void stage64(const char* gbase, int rowStrideBytes, char* lds, int tid) {
    const int lane = tid & 63;
    const int w = tid >> 6;           // 0..3
    const int lr = lane >> 3;
    const int cb = (lane & 7) << 4;
    #pragma unroll
    for (int j = 0; j < 2; ++j) {
        const int seg = j * 4 + w;          // 0..7
        const int row = seg * 8 + lr;       // 0..63
        const int sb = cb ^ ((row & 7) << 4);
        gload_lds16(gbase + (size_t)row * rowStrideBytes + sb,
                    lds + seg * 1024);
    }
}

// ---- 512-thread (8-wave) stage of a 128x64-bf16 tile: 2 issues/thread ----
__device__ inline void stage128(const char* gRow0, int rowStrideBytes, char* ldsBase, int tid) {
    const int lane = tid & 63;
    const int w = tid >> 6;           // 0..7
    const int lr = lane >> 3;
    #pragma unroll
    for (int j = 0; j < 2; ++j) {
        const int seg = w * 2 + j;          // 0..15
        const int row = seg * 8 + lr;       // 0..127
        const int sb = ((lane & 7) << 4) ^ ((row & 7) << 4);
        gload_lds16(gRow0 + (size_t)row * rowStrideBytes + sb,
                    ldsBase + seg * 1024);
    }
}

// Swizzled ds_read_b128 of an MFMA fragment (8 bf16 along K at one row).
// Row stride 128 B; valid for any contiguous row count.
__device__ inline s16x8 read_frag(const u16* lds, int row, int colByte) {
    const int bir = colByte ^ ((row & 7) << 4);
    return *(const s16x8*)((const char*)lds + row * 128 + bir);
}

// ---------- prep kernels ----------
__global__ void prep_weights(const float* __restrict__ Wg_in, const float* __restrict__ Wg_out,
                             const float* __restrict__ W_in,  const float* __restrict__ W_out,
                             const float* __restrict__ W_loop, const float* __restrict__ sent,
                             u16* __restrict__ Wg_all, u16* __restrict__ W_all,
                             u16* __restrict__ Wl, u16* __restrict__ X0) {
    const int i4 = blockIdx.x * blockDim.x + threadIdx.x;   // float4 index
    const int NW4 = L_ * K_ * H_ * H_ / 4;
    const int KHH4 = K_ * H_ * H_ / 4;
    if (i4 < NW4) {
        const int l = i4 / KHH4;
        const int rem = i4 - l * KHH4;
        const int d0 = (l * 2) * KHH4 + rem;
        const int d1 = d0 + KHH4;
        ((ushort4*)Wg_all)[d0] = f2bf4(((const float4*)Wg_in)[i4]);
        ((ushort4*)Wg_all)[d1] = f2bf4(((const float4*)Wg_out)[i4]);
        ((ushort4*)W_all)[d0]  = f2bf4(((const float4*)W_in)[i4]);
        ((ushort4*)W_all)[d1]  = f2bf4(((const float4*)W_out)[i4]);
    }
    if (i4 < L_ * H_ * H_ / 4)  ((ushort4*)Wl)[i4] = f2bf4(((const float4*)W_loop)[i4]);
    if (i4 < T_ * H_ / 4)       ((ushort4*)X0)[i4] = f2bf4(((const float4*)sent)[i4]);
}

// adjA[p][b][t][s]: p=dir*4+k; dir 0 (in): adj[b,k,s,t] (transposed), dir 1 (out): adj[b,k,t,s]
__global__ void prep_adj(const float* __restrict__ adj, u16* __restrict__ adjA) {
    const int idx = blockIdx.x * blockDim.x + threadIdx.x;
    const int s = idx & 127;
    const int t = (idx >> 7) & 127;
    const int b = (idx >> 14) & 15;
    const int p = idx >> 18;
    const int dir = p >> 2, k = p & 3;
    const float v = dir ? adj[(((size_t)b * K_ + k) * S_ + t) * S_ + s]
                        : adj[(((size_t)b * K_ + k) * S_ + s) * S_ + t];
    adjA[idx] = f2bf(v);
}

// ---------- GEMM 1: gated weight GEMMs + self loop ----------
// 2-phase double-buffered (stage t+1 issued before compute t, one barrier/K-tile).
// Tile: 256 tokens x 128 h (rel+gate both computed), 8 waves 4m x 2n,
// per-wave 64x64 rel + 64x64 gate. BK=64, LDS 2 x (A32K + Br16K + Bg16K) = 128 KiB.
// grid (6 n-tiles, 8 m-tiles, 9 problems), block 512.
__global__ __launch_bounds__(512, 2)
void gemm1_kernel(const u16* __restrict__ Xb,
                  const u16* __restrict__ Wg_all, const u16* __restrict__ W_all,
                  const u16* __restrict__ Wl,
                  const float* __restrict__ bg_in, const float* __restrict__ bg_out,
                  const float* __restrict__ b_in,  const float* __restrict__ b_out,
                  int layer,
                  u16* __restrict__ Rel2, float* __restrict__ SBuf) {
    __shared__ __align__(16) char smem[131072];

    const int tid = threadIdx.x;
    const int lane = tid & 63;
    const int w = tid >> 6;
    const int wm = w >> 1;                 // 0..3
    const int wn = w & 1;                  // 0..1
    const int l15 = lane & 15;
    const int hi16 = (lane >> 4) << 4;
    const int p = blockIdx.z;
    const bool gated = (p < 8);
    if (!gated && blockIdx.x >= 3) return;
    const int m0 = blockIdx.y * 256;
    const int n0 = gated ? blockIdx.x * 128 : blockIdx.x * 256;

    const u16* Wr;
    const u16* Wg = nullptr;
    if (gated) {
        const int dir = p >> 2, k = p & 3;
        const size_t woff = ((size_t)(layer * 2 + dir) * K_ + k) * (size_t)(H_ * H_);
        Wg = Wg_all + woff;
        Wr = W_all + woff;
    } else {
        Wr = Wl + (size_t)layer * H_ * H_;
    }

    const char* gA  = (const char*)Xb + (size_t)m0 * (H_ * 2);
    const char* gBr = (const char*)Wr + (size_t)n0 * (H_ * 2);
    const char* gBg = gated ? ((const char*)Wg + (size_t)n0 * (H_ * 2))
                            : (gBr + (size_t)128 * (H_ * 2));

    auto STAGE = [&](int kt, int c) {
        char* base = smem + c * 65536;
        stage128(gA + (size_t)kt * 128, H_ * 2, base, tid);
        stage128(gA + (size_t)128 * (H_ * 2) + (size_t)kt * 128, H_ * 2, base + 16384, tid);
        stage128(gBr + (size_t)kt * 128, H_ * 2, base + 32768, tid);
        stage128(gBg + (size_t)kt * 128, H_ * 2, base + 49152, tid);
    };

    const f32x4 zf = {0.f, 0.f, 0.f, 0.f};
    f32x4 accr[4][4], accg[4][4];
    #pragma unroll
    for (int i = 0; i < 4; ++i)
        #pragma unroll
        for (int j = 0; j < 4; ++j) { accr[i][j] = zf; accg[i][j] = zf; }

    STAGE(0, 0);
    __syncthreads();

    for (int t = 0; t < 12; ++t) {
        const int c = t & 1;
        if (t < 11) STAGE(t + 1, c ^ 1);          // prefetch next tile first
        const u16* lA  = (const u16*)(smem + c * 65536);
        const u16* lBr = (const u16*)(smem + c * 65536 + 32768);
        const u16* lBg = (const u16*)(smem + c * 65536 + 49152);
        #pragma unroll
        for (int kq = 0; kq < 2; ++kq) {
            const int ck = kq * 64 + hi16;
            s16x8 a[4], br[4], bg[4];
            #pragma unroll
            for (int i = 0; i < 4; ++i)
                a[i] = read_frag(lA, wm * 64 + i * 16 + l15, ck);
            #pragma unroll
            for (int j = 0; j < 4; ++j)
                br[j] = read_frag(lBr, wn * 64 + j * 16 + l15, ck);
            #pragma unroll
            for (int j = 0; j < 4; ++j)
                bg[j] = read_frag(lBg, wn * 64 + j * 16 + l15, ck);
            #pragma unroll
            for (int i = 0; i < 4; ++i) {
                #pragma unroll
                for (int j = 0; j < 4; ++j) {
                    accr[i][j] = mfma16(a[i], br[j], accr[i][j]);
                    accg[i][j] = mfma16(a[i], bg[j], accg[i][j]);
                }
            }
        }
        __syncthreads();
    }

    // ---------------- epilogue (wave-local, no LDS) ----------------
    if (gated) {
        const int dir = p >> 2, k = p & 3;
        const float* bgp = (dir ? bg_out : bg_in) + ((size_t)layer * K_ + k) * H_;
        const float* brp = (dir ? b_out  : b_in ) + ((size_t)layer * K_ + k) * H_;
        #pragma unroll
        for (int j = 0; j < 4; ++j) {
            const int h = n0 + wn * 64 + j * 16 + l15;
            const float bgv = bgp[h];
            const float brv = brp[h];
            #pragma unroll
            for (int i = 0; i < 4; ++i) {
                const int tl = wm * 64 + i * 16 + ((lane >> 4) << 2);   // 0..255
                const int b = blockIdx.y * 2 + (tl >> 7);
                const int s0 = tl & 127;
                u16 tmp[4];
                #pragma unroll
                for (int r = 0; r < 4; ++r) {
                    const float g = accg[i][j][r] + bgv;
                    const float v = accr[i][j][r] + brv;
                    tmp[r] = f2bf(0.5f * v / (1.f + __expf(-g)));
                }
                ushort4 pk; pk.x = tmp[0]; pk.y = tmp[1]; pk.z = tmp[2]; pk.w = tmp[3];
                *(ushort4*)(Rel2 + (((size_t)p * B_ + b) * H_ + h) * S_ + s0) = pk;
            }
        }
    } else {
        #pragma unroll
        for (int j = 0; j < 4; ++j) {
            const int h1 = n0 + wn * 64 + j * 16 + l15;
            const int h2 = h1 + 128;
            #pragma unroll
            for (int i = 0; i < 4; ++i) {
                const int tg = m0 + wm * 64 + i * 16 + ((lane >> 4) << 2);
                #pragma unroll
                for (int r = 0; r < 4; ++r) {
                    SBuf[(size_t)(tg + r) * H_ + h1] = accr[i][j][r];
                    SBuf[(size_t)(tg + r) * H_ + h2] = accg[i][j][r];
                }
            }
        }
    }
}

// ---------- GEMM 2: adjacency contraction + loop term + ReLU ----------
// 2-phase dbuf; grid (12 h-tiles of 64, 16 batches), block 256 (4 waves 2x2).
__global__ __launch_bounds__(256, 2)
void gemm2_kernel(const u16* __restrict__ adjA, const u16* __restrict__ Rel2,
                  const float* __restrict__ SBuf,
                  u16* __restrict__ Xn, float* __restrict__ Out, int lastLayer) {
    __shared__ __align__(16) char smem2[49152];   // 2 x (A 16K + B 8K)

    const int tid = threadIdx.x;
    const int lane = tid & 63;
    const int w = tid >> 6;
    const int wm = w >> 1, wn = w & 1;
    const int l15 = lane & 15;
    const int hi16 = (lane >> 4) << 4;
    const int h0 = blockIdx.x * 64;
    const int b = blockIdx.y;

    auto STAGE = [&](int q, int c) {
        const int p = q >> 1, sc = q & 1;
        const char* Ab = (const char*)adjA + ((size_t)p * B_ + b) * (S_ * S_ * 2) + sc * 128;
        const char* Bb = (const char*)Rel2 + (((size_t)p * B_ + b) * H_ + h0) * (S_ * 2) + sc * 128;
        char* base = smem2 + c * 24576;
        stage_tile(Ab, S_ * 2, (u16*)base, tid);
        stage64(Bb, S_ * 2, base + 16384, tid);
    };

    const f32x4 zf = {0.f, 0.f, 0.f, 0.f};
    f32x4 acc[4][2];
    #pragma unroll
    for (int i = 0; i < 4; ++i)
        #pragma unroll
        for (int j = 0; j < 2; ++j) acc[i][j] = zf;

    STAGE(0, 0);
    __syncthreads();

    for (int q = 0; q < 16; ++q) {
        const int c = q & 1;
        if (q < 15) STAGE(q + 1, c ^ 1);
        const u16* lA = (const u16*)(smem2 + c * 24576);
        const u16* lB = (const u16*)(smem2 + c * 24576 + 16384);
        #pragma unroll
        for (int kq = 0; kq < 2; ++kq) {
            const int ck = kq * 64 + hi16;
            s16x8 a[4], bb[2];
            #pragma unroll
            for (int i = 0; i < 4; ++i)
                a[i] = read_frag(lA, wm * 64 + i * 16 + l15, ck);
            #pragma unroll
            for (int j = 0; j < 2; ++j)
                bb[j] = read_frag(lB, wn * 32 + j * 16 + l15, ck);
            #pragma unroll
            for (int i = 0; i < 4; ++i)
                #pragma unroll
                for (int j = 0; j < 2; ++j)
                    acc[i][j] = mfma16(a[i], bb[j], acc[i][j]);
        }
        __syncthreads();
    }

    #pragma unroll
    for (int i = 0; i < 4; ++i) {
        const int tl = wm * 64 + i * 16 + ((lane >> 4) << 2);
        #pragma unroll
        for (int j = 0; j < 2; ++j) {
            const int h = h0 + wn * 32 + j * 16 + l15;
            #pragma unroll
            for (int r = 0; r < 4; ++r) {
                const size_t t = (size_t)b * S_ + tl + r;
                float v = acc[i][j][r] + SBuf[t * H_ + h];
                v = fmaxf(v, 0.f);
                if (lastLayer) Out[t * H_ + h] = v;
                else           Xn[t * H_ + h] = f2bf(v);
            }
        }
    }
}

// ---------- launch ----------
extern "C" void kernel_launch(void* const* d_in, const int* in_sizes, int n_in,
                              void* d_out, int out_size, void* d_ws, size_t ws_size,
                              hipStream_t stream) {
    const float* sent   = (const float*)d_in[0];
    const float* adj    = (const float*)d_in[1];
    const float* W_in   = (const float*)d_in[2];
    const float* b_in   = (const float*)d_in[3];
    const float* W_out  = (const float*)d_in[4];
    const float* b_out  = (const float*)d_in[5];
    const float* Wg_in  = (const float*)d_in[6];
    const float* bg_in  = (const float*)d_in[7];
    const float* Wg_out = (const float*)d_in[8];
    const float* bg_out = (const float*)d_in[9];
    const float* W_loop = (const float*)d_in[10];

    char* ws = (char*)d_ws;
    u16* Wg_all = (u16*)(ws);                  // 18,874,368 B
    u16* W_all  = (u16*)(ws + 18874368);       // 18,874,368 B
    u16* Wl     = (u16*)(ws + 37748736);       //  2,359,296 B
    u16* adjA   = (u16*)(ws + 40108032);       //  4,194,304 B
    u16* X0     = (u16*)(ws + 44302336);       //  3,145,728 B
    u16* X1     = (u16*)(ws + 47448064);       //  3,145,728 B
    u16* Rel2   = (u16*)(ws + 50593792);       // 25,165,824 B
    float* SBuf = (float*)(ws + 75759616);     //  6,291,456 B  (end 82,051,072)

    prep_weights<<<4608, 256, 0, stream>>>(Wg_in, Wg_out, W_in, W_out, W_loop, sent,
                                           Wg_all, W_all, Wl, X0);
    prep_adj<<<8192, 256, 0, stream>>>(adj, adjA);

    u16* Xc = X0;
    u16* Xn = X1;
    for (int l = 0; l < L_; ++l) {
        gemm1_kernel<<<dim3(6, 8, 9), 512, 0, stream>>>(Xc, Wg_all, W_all, Wl,
                                                        bg_in, bg_out, b_in, b_out,
                                                        l, Rel2, SBuf);
        gemm2_kernel<<<dim3(12, 16), 256, 0, stream>>>(adjA, Rel2, SBuf, Xn,
                                                       (float*)d_out, l == L_ - 1);
        u16* t = Xc; Xc = Xn; Xn = t;
    }
}